// Round 15
// baseline (165.787 us; speedup 1.0000x reference)
//
#include <hip/hip_runtime.h>
#include <hip/hip_bf16.h>
#include <math.h>

#define BB 4
#define NN 4096
#define KK 32
#define HH 128

#define NPB 64        // nodes per block -> grid 256 = exactly 1 block/CU
#define THREADS 512   // 8 waves, 8 nodes per wave
#define NPI (NPB / 8) // nodes per wave
#define NBLK ((BB * NN) / NPB)       // 256 blocks
#define BPB (NBLK / BB)              // 64 blocks per batch

typedef short bf16x8 __attribute__((ext_vector_type(8)));
typedef float f32x16 __attribute__((ext_vector_type(16)));
typedef float f32x2  __attribute__((ext_vector_type(2)));
typedef unsigned int u32;

// LDS map (145.25 KB -> 1 block/CU). r8/r13's proven no-spill structure:
// H0 staged in per-wave LDS, W1/W2 frag tables in LDS, one acc tile at a time.
#define OFF_W1   0
#define OFF_W2   32768
#define OFF_H0   65536                     // 8 waves x 8 ks x 64 lanes x 16 B = 65536 B
#define OFF_SELF (OFF_H0 + 65536)          // 64 nodes x 128 bf16 = 16384 B
#define OFF_WD   (OFF_SELF + NPB*HH*2)     // 256 B
#define OFF_B1   (OFF_WD + HH*2)           // 512 B (f32 b1)
#define OFF_B2   (OFF_B1 + HH*4)           // 512 B (f32 b2)
#define LDS_TOTAL (OFF_B2 + HH*4)          // 148736 B

#define MFMA(a,b,c) __builtin_amdgcn_mfma_f32_32x32x16_bf16(a,b,c,0,0,0)

// cheap bf16 pair pack: +0x8000 round + v_perm (3 VALU)
__device__ __forceinline__ u32 pack_bf2(float lo, float hi) {
    u32 ul, uh;
    __builtin_memcpy(&ul, &lo, 4);
    __builtin_memcpy(&uh, &hi, 4);
    return __builtin_amdgcn_perm(uh + 0x8000u, ul + 0x8000u, 0x07060302u);
}
__device__ __forceinline__ short f2bfs(float v) {
    __hip_bfloat16 h = __float2bfloat16(v);
    short r; __builtin_memcpy(&r, &h, 2); return r;
}
// unpack a u32 holding two bf16 -> f32x2 (2 bit-ops, then VGPR pair)
__device__ __forceinline__ f32x2 unpk2(u32 w) {
    u32 lo = w << 16;
    u32 hi2 = w & 0xffff0000u;
    float flo, fhi;
    __builtin_memcpy(&flo, &lo, 4);
    __builtin_memcpy(&fhi, &hi2, 4);
    return (f32x2){flo, fhi};
}
// tanh-form GELU on a pair — vector ops map to v_pk_{mul,fma,add}_f32 (VOP3P
// packed f32, gfx90a+): halves VALU issue slots for the polynomial part.
// exp2/rcp stay scalar trans (no packed variant). Same arithmetic as before.
__device__ __forceinline__ f32x2 gelu2(f32x2 x) {
    f32x2 x2 = x * x;
    f32x2 t = x * (x2 * 0.10294828f + 2.30220913f);  // 2u*log2(e) poly
    f32x2 e;
    e.x = exp2f(t.x);
    e.y = exp2f(t.y);
    f32x2 ep = e + 1.0f;
    f32x2 r;
    r.x = __builtin_amdgcn_rcpf(ep.x);
    r.y = __builtin_amdgcn_rcpf(ep.y);
    return x - x * r;                                 // contracts to pk_fma
}

union frag { bf16x8 v; u32 w[4]; };

// ---------------------------------------------------------------------------
// Kernel A: Ysrc = bf16((enc*mask) @ W0[0:128]), Yself = bf16(.. @ W0[128:256] + b0)
// ---------------------------------------------------------------------------
__global__ __launch_bounds__(128) void precompute_kernel(
    const float* __restrict__ enc, const float* __restrict__ mask,
    const float* __restrict__ W0, const float* __restrict__ b0,
    __hip_bfloat16* __restrict__ Ysrc, __hip_bfloat16* __restrict__ Yself)
{
    const int tid = threadIdx.x;
    const int wave = tid >> 6;
    const int lane = tid & 63;
    const int li = lane & 31;
    const int hi = lane >> 5;
    const int rowBase = blockIdx.x * 64 + wave * 32;
    const int myrow = rowBase + li;

    const float m = mask[myrow];
    bf16x8 A[8];
    #pragma unroll
    for (int ks = 0; ks < 8; ++ks) {
        const float* p = enc + (size_t)myrow * HH + ks * 16 + hi * 8;
        float4 a = *(const float4*)p;
        float4 c = *(const float4*)(p + 4);
        frag f;
        f.w[0] = pack_bf2(a.x * m, a.y * m);
        f.w[1] = pack_bf2(a.z * m, a.w * m);
        f.w[2] = pack_bf2(c.x * m, c.y * m);
        f.w[3] = pack_bf2(c.z * m, c.w * m);
        A[ks] = f.v;
    }

    #pragma unroll
    for (int h2 = 0; h2 < 2; ++h2) {
        __hip_bfloat16* dest = h2 ? Yself : Ysrc;
        #pragma unroll 1
        for (int mt = 0; mt < 4; ++mt) {
            const float bias = h2 ? b0[mt * 32 + li] : 0.0f;
            f32x16 acc;
            #pragma unroll
            for (int r = 0; r < 16; ++r) acc[r] = 0.f;
            #pragma unroll
            for (int ks = 0; ks < 8; ++ks) {
                bf16x8 Bf;
                #pragma unroll
                for (int j = 0; j < 8; ++j) {
                    int k = ks * 16 + hi * 8 + j;
                    Bf[j] = f2bfs(W0[(size_t)(h2 * HH + k) * HH + mt * 32 + li]);
                }
                acc = MFMA(A[ks], Bf, acc);
            }
            #pragma unroll
            for (int r = 0; r < 16; ++r) {
                int rrow = (r & 3) + 8 * (r >> 2) + 4 * hi;
                dest[(size_t)(rowBase + rrow) * HH + mt * 32 + li] =
                    __float2bfloat16(acc[r] + bias);
            }
        }
    }
}

// ---------------------------------------------------------------------------
// Kernel B: per-edge MLP + masked mean + fused per-block stats partials.
// r13/r14 no-spill structure; elementwise phases rewritten on f32x2 so the
// backend emits packed v_pk_*_f32 (2 lanes per VALU issue slot).
// ---------------------------------------------------------------------------
__global__ __launch_bounds__(THREADS) void mpnn_kernel(
    const float* __restrict__ enc, const float* __restrict__ mask,
    const float* __restrict__ dist, const int* __restrict__ eidx,
    const __hip_bfloat16* __restrict__ Ysrc, const __hip_bfloat16* __restrict__ Yself,
    const float* __restrict__ W0,
    const float* __restrict__ W1, const float* __restrict__ b1,
    const float* __restrict__ W2, const float* __restrict__ b2,
    float* __restrict__ upd, float* __restrict__ psum2, float* __restrict__ psumsq2)
{
    extern __shared__ char lds[];
    const int tid  = threadIdx.x;
    const int wave = tid >> 6;
    const int lane = tid & 63;
    const int li   = lane & 31;
    const int hi   = lane >> 5;
    const int nodeBase = blockIdx.x * NPB;

    // ---- stage W1/W2 fragment tables (bf16, MFMA frag layout) ----
    #pragma unroll
    for (int tbl = 0; tbl < 2; ++tbl) {
        const float* W = tbl ? W2 : W1;
        short* dst = (short*)(lds + tbl * 32768);
        #pragma unroll
        for (int i = 0; i < (HH * HH) / THREADS; ++i) {
            int e = i * THREADS + tid;
            int feat = e & 127, k = e >> 7;
            float v = W[(size_t)k * HH + feat];
            int mt = feat >> 5, ks = k >> 4, h2 = (k >> 3) & 1, j = k & 7;
            dst[((mt * 8 + ks) * 64 + h2 * 32 + (feat & 31)) * 8 + j] = f2bfs(v);
        }
    }
    {
        uint4* sv = (uint4*)(lds + OFF_SELF);
        sv[tid]       = *(const uint4*)(Yself + (size_t)nodeBase * HH + tid * 8);
        sv[tid + 512] = *(const uint4*)(Yself + (size_t)nodeBase * HH + (tid + 512) * 8);
    }
    short* swd = (short*)(lds + OFF_WD);
    if (tid < HH) swd[tid] = f2bfs(W0[(size_t)256 * HH + tid]);
    float* s_b1f = (float*)(lds + OFF_B1);
    if (tid < HH) s_b1f[tid] = b1[tid];
    float* s_b2f = (float*)(lds + OFF_B2);
    if (tid < HH) s_b2f[tid] = b2[tid];
    __syncthreads();

    const int b = nodeBase >> 12;
    const __hip_bfloat16* YsB = Ysrc + (size_t)b * NN * HH;
    // per-wave H0 staging buffer: [ks][lane] x 16 B
    char* h0buf = lds + OFF_H0 + (size_t)wave * 8 * 64 * 16;

    // fused-stats accumulators for this thread's two fixed features
    float st_s0 = 0.f, st_q0 = 0.f, st_s1 = 0.f, st_q1 = 0.f;

    // ---- prologue: gather + meta for first node ----
    const int node0 = wave * NPI;
    int   ie = eidx[(size_t)(nodeBase + node0) * KK + li];
    float dd = dist[(size_t)(nodeBase + node0) * KK + li];
    float mk = mask[nodeBase + node0];
    bf16x8 g[8];
    {
        int ic0 = ie < 0 ? 0 : ie;
        const char* gb = (const char*)(YsB + (size_t)ic0 * HH) + hi * 16;
        #pragma unroll
        for (int ks = 0; ks < 8; ++ks) g[ks] = *(const bf16x8*)(gb + ks * 32);
    }

    #pragma unroll 1
    for (int i = 0; i < NPI; ++i) {
        const int node_local = node0 + i;
        const int gnode = nodeBase + node_local;

        // snapshot current node's scalars before prefetch overwrites them
        bool valid = ie >= 0;
        u32 vmask = (u32)__ballot(valid);
        int vc = __popc(vmask);
        float inv_vc = 1.0f / (float)(vc < 1 ? 1 : vc);
        float dste = dd;
        float mask_n = mk;

        // ---- layer 0: elementwise add/gelu -> H0 to LDS (g dies here) ----
        const short* sself = (const short*)(lds + OFF_SELF) + node_local * HH;
        const f32x2 d2 = {dste, dste};
        #pragma unroll
        for (int ks = 0; ks < 8; ++ks) {
            frag gg; gg.v = g[ks];
            frag yy; yy.v = *(const bf16x8*)(sself + ks * 16 + hi * 8);
            frag dw; dw.v = *(const bf16x8*)(swd + ks * 16 + hi * 8);
            frag h;
            #pragma unroll
            for (int q = 0; q < 4; ++q) {
                f32x2 z = unpk2(gg.w[q]) + unpk2(yy.w[q]) + d2 * unpk2(dw.w[q]);
                f32x2 hv = gelu2(z);
                h.w[q] = pack_bf2(hv.x, hv.y);
            }
            *(bf16x8*)(h0buf + (ks * 64 + lane) * 16) = h.v;
        }

        // ---- prefetch next node's gather + meta (hides under layers 1-2) ----
        if (i + 1 < NPI) {
            ie = eidx[(size_t)(gnode + 1) * KK + li];
            dd = dist[(size_t)(gnode + 1) * KK + li];
            mk = mask[gnode + 1];
            int icn = ie < 0 ? 0 : ie;
            const char* gb = (const char*)(YsB + (size_t)icn * HH) + hi * 16;
            #pragma unroll
            for (int ks = 0; ks < 8; ++ks) g[ks] = *(const bf16x8*)(gb + ks * 32);
        }

        // ---- layer 1 (transposed): per mt-tile, B re-read from LDS ----
        frag F2[8];
        #pragma unroll
        for (int mt = 0; mt < 4; ++mt) {
            f32x16 acc;
            #pragma unroll
            for (int r = 0; r < 16; ++r) acc[r] = 0.f;
            #pragma unroll
            for (int ks = 0; ks < 8; ++ks) {
                bf16x8 a = *(const bf16x8*)(lds + OFF_W1 + ((mt * 8 + ks) * 64 + lane) * 16);
                bf16x8 h0 = *(const bf16x8*)(h0buf + (ks * 64 + lane) * 16);
                acc = MFMA(a, h0, acc);
            }
            u32 pk8[8];
            #pragma unroll
            for (int q = 0; q < 8; ++q) {
                int row0 = 8 * (q >> 1) + 2 * (q & 1) + 4 * hi;   // rows row0,row0+1
                f32x2 bb = *(const f32x2*)(s_b1f + mt * 32 + row0);
                f32x2 av = {acc[2*q], acc[2*q+1]};
                f32x2 hv = gelu2(av + bb);
                pk8[q] = pack_bf2(hv.x, hv.y);
            }
            #pragma unroll
            for (int e = 0; e < 2; ++e) {
                const int ks = 2 * mt + e;
                #pragma unroll
                for (int r = 0; r < 4; ++r) {
                    const int q0 = (r & 1) + 4 * e;
                    u32 own  = hi ? pk8[q0 + 2] : pk8[q0];
                    u32 give = hi ? pk8[q0]     : pk8[q0 + 2];
                    u32 got  = (u32)__shfl_xor((int)give, 32, 64);
                    F2[ks].w[r] = ((r >> 1) == hi) ? own : got;
                }
            }
        }

        // ---- layer 2 (normal), one nt-tile at a time -> scalars ----
        float s0, s1, s2, s3;
        #pragma unroll
        for (int nt = 0; nt < 4; ++nt) {
            f32x16 acc;
            #pragma unroll
            for (int r = 0; r < 16; ++r) acc[r] = 0.f;
            #pragma unroll
            for (int ks = 0; ks < 8; ++ks) {
                bf16x8 w2f = *(const bf16x8*)(lds + OFF_W2 + ((nt * 8 + ks) * 64 + lane) * 16);
                acc = MFMA(F2[ks].v, w2f, acc);
            }
            float bv = s_b2f[nt * 32 + li];
            const f32x2 bv2 = {bv, bv};
            float t = 0.f;
            #pragma unroll
            for (int q = 0; q < 8; ++q) {
                f32x2 av = {acc[2*q], acc[2*q+1]};
                f32x2 v2 = gelu2(av + bv2);
                int r0 = 2*q, r1 = 2*q + 1;
                int e0 = (r0 & 3) + 8 * (r0 >> 2) + 4 * hi;
                int e1 = (r1 & 3) + 8 * (r1 >> 2) + 4 * hi;
                t += ((vmask >> e0) & 1) ? v2.x : 0.f;
                t += ((vmask >> e1) & 1) ? v2.y : 0.f;
            }
            t += __shfl_xor(t, 32, 64);
            if (nt == 0) s0 = t; else if (nt == 1) s1 = t;
            else if (nt == 2) s2 = t; else s3 = t;
        }

        // ---- epilogue: thread writes feats (hi*2)*32+li and (hi*2+1)*32+li ----
        float sa = hi ? s2 : s0;
        float sb = hi ? s3 : s1;
        int f0 = (hi * 2) * 32 + li;
        int f1 = (hi * 2 + 1) * 32 + li;
        float u0 = (enc[(size_t)gnode * HH + f0] + sa * inv_vc) * mask_n;
        float u1 = (enc[(size_t)gnode * HH + f1] + sb * inv_vc) * mask_n;
        upd[(size_t)gnode * HH + f0] = u0;
        upd[(size_t)gnode * HH + f1] = u1;
        st_s0 += u0; st_q0 = fmaf(u0, u0, st_q0);
        st_s1 += u1; st_q1 = fmaf(u1, u1, st_q1);
    }

    // ---- fused stats: block-level partials per feature (reuses H0 region) ----
    __syncthreads();
    float4* red = (float4*)(lds + OFF_H0);
    red[tid] = make_float4(st_s0, st_q0, st_s1, st_q1);
    __syncthreads();
    if (tid < HH) {
        const int f = tid;
        const int q = f >> 5;
        const int rl = (q >> 1) * 32 + (f & 31);  // lane within each wave
        const bool use1 = (q & 1) != 0;
        float s = 0.f, sq = 0.f;
        #pragma unroll
        for (int w = 0; w < 8; ++w) {
            float4 v = red[w * 64 + rl];
            s  += use1 ? v.z : v.x;
            sq += use1 ? v.w : v.y;
        }
        psum2[(size_t)blockIdx.x * HH + f]   = s;
        psumsq2[(size_t)blockIdx.x * HH + f] = sq;
    }
}

// ---------------------------------------------------------------------------
// Kernel 2b: combine per-block partials -> mean, 1/std per (b, feature)
// ---------------------------------------------------------------------------
__global__ __launch_bounds__(128) void finalize_stats_kernel(
    const float* __restrict__ psum2, const float* __restrict__ psumsq2,
    const float* __restrict__ mask, float* __restrict__ meanp, float* __restrict__ istdp)
{
    const int b = blockIdx.x;
    const int j = threadIdx.x;
    float s = 0.f, s2 = 0.f;
    #pragma unroll 4
    for (int c = 0; c < BPB; ++c) {
        s  += psum2[((size_t)(b * BPB + c)) * HH + j];
        s2 += psumsq2[((size_t)(b * BPB + c)) * HH + j];
    }
    float cpart = 0.f;
    #pragma unroll 4
    for (int t = 0; t < NN / HH; ++t)
        cpart += mask[(size_t)b * NN + (size_t)t * HH + j];
    __shared__ float red[HH];
    red[j] = cpart;
    __syncthreads();
    for (int off = HH / 2; off > 0; off >>= 1) {
        if (j < off) red[j] += red[j + off];
        __syncthreads();
    }
    float counts = red[0];
    if (counts == 0.f) counts = 1.f;
    float mean = s / counts;
    float var  = (s2 - 2.f * mean * s + (float)NN * mean * mean) / counts;
    meanp[b * HH + j] = mean;
    istdp[b * HH + j] = 1.0f / sqrtf(var + 1e-5f);
}

// ---------------------------------------------------------------------------
// Kernel 3: normalize out0 in place + write pass-through outputs
// ---------------------------------------------------------------------------
__global__ void write_out_kernel(
    const float* __restrict__ mask, const float* __restrict__ dist,
    const int* __restrict__ eidx, const float* __restrict__ meanp,
    const float* __restrict__ istdp, const float* __restrict__ scale,
    const float* __restrict__ shift, float* __restrict__ out)
{
    const size_t T0 = (size_t)BB * NN * HH;
    const size_t T1 = (size_t)BB * NN;
    const size_t T2 = (size_t)BB * NN * KK;
    const size_t stride = (size_t)gridDim.x * blockDim.x;
    const size_t t = (size_t)blockIdx.x * blockDim.x + threadIdx.x;

    for (size_t x = t; x < T0; x += stride) {
        int h = (int)(x & (HH - 1));
        size_t bn = x >> 7;
        int b = (int)(bn >> 12);
        float m = mask[bn];
        float v = (out[x] - meanp[b * HH + h]) * istdp[b * HH + h] * scale[h] + shift[h];
        out[x] = v * m;
    }
    float* out1 = out + T0;
    for (size_t x = t; x < T1; x += stride) out1[x] = mask[x];
    float* out2 = out1 + T1;
    for (size_t x = t; x < T2; x += stride) out2[x] = dist[x];
    float* out3 = out2 + T2;
    for (size_t x = t; x < T2; x += stride) out3[x] = (float)eidx[x];
}

// ---------------------------------------------------------------------------
extern "C" void kernel_launch(void* const* d_in, const int* in_sizes, int n_in,
                              void* d_out, int out_size, void* d_ws, size_t ws_size,
                              hipStream_t stream) {
    const float* enc   = (const float*)d_in[0];
    const float* mask  = (const float*)d_in[1];
    const float* dist  = (const float*)d_in[2];
    const int*   eidx  = (const int*)  d_in[3];
    const float* W0    = (const float*)d_in[4];
    const float* b0    = (const float*)d_in[5];
    const float* W1    = (const float*)d_in[6];
    const float* b1    = (const float*)d_in[7];
    const float* W2    = (const float*)d_in[8];
    const float* b2    = (const float*)d_in[9];
    const float* scale = (const float*)d_in[10];
    const float* shift = (const float*)d_in[11];
    float* out = (float*)d_out;
    float* upd = out;   // pre-norm upd lives in out[0:B*N*H], normalized in place later

    const size_t T0 = (size_t)BB * NN * HH;
    const size_t T1 = (size_t)BB * NN;

    __hip_bfloat16* Ysrc  = (__hip_bfloat16*)d_ws;                 // 4 MB
    __hip_bfloat16* Yself = (__hip_bfloat16*)(out + T0 + T1);      // 4 MB (out2/out3 region, overwritten last)
    float* wsf     = (float*)((char*)d_ws + (size_t)BB * NN * HH * 2);
    float* psum2   = wsf;                                          // 256*128 = 128 KB
    float* psumsq2 = psum2 + (size_t)NBLK * HH;                    // 128 KB
    float* meanp   = psumsq2 + (size_t)NBLK * HH;
    float* istdp   = meanp + (size_t)BB * HH;

    hipFuncSetAttribute((const void*)mpnn_kernel,
                        hipFuncAttributeMaxDynamicSharedMemorySize, LDS_TOTAL);

    precompute_kernel<<<dim3(256), dim3(128), 0, stream>>>(enc, mask, W0, b0, Ysrc, Yself);
    mpnn_kernel<<<dim3(NBLK), dim3(THREADS), LDS_TOTAL, stream>>>(
        enc, mask, dist, eidx, Ysrc, Yself, W0, W1, b1, W2, b2, upd, psum2, psumsq2);
    finalize_stats_kernel<<<dim3(BB), dim3(128), 0, stream>>>(psum2, psumsq2, mask, meanp, istdp);
    write_out_kernel<<<dim3(1024), dim3(256), 0, stream>>>(
        mask, dist, eidx, meanp, istdp, scale, shift, out);
}

// Round 16
// 156.433 us; speedup vs baseline: 1.0598x; 1.0598x over previous
//
#include <hip/hip_runtime.h>
#include <hip/hip_bf16.h>
#include <math.h>

#define BB 4
#define NN 4096
#define KK 32
#define HH 128

#define NPB 64        // nodes per block -> grid 256 = exactly 1 block/CU
#define THREADS 512   // 8 waves, 8 nodes per wave
#define NPI (NPB / 8) // nodes per wave
#define NBLK ((BB * NN) / NPB)       // 256 blocks
#define BPB (NBLK / BB)              // 64 blocks per batch

typedef short bf16x8 __attribute__((ext_vector_type(8)));
typedef float f32x16 __attribute__((ext_vector_type(16)));
typedef float f32x2  __attribute__((ext_vector_type(2)));
typedef unsigned int u32;

// LDS map (145.25 KB -> 1 block/CU). r8/r13 no-spill structure.
#define OFF_W1   0
#define OFF_W2   32768
#define OFF_H0   65536                     // 8 waves x 8 ks x 64 lanes x 16 B
#define OFF_SELF (OFF_H0 + 65536)          // 64 nodes x 128 bf16 = 16384 B
#define OFF_WD   (OFF_SELF + NPB*HH*2)     // 256 B
#define OFF_B1   (OFF_WD + HH*2)           // 512 B (f32 b1)
#define OFF_B2   (OFF_B1 + HH*4)           // 512 B (f32 b2)
#define LDS_TOTAL (OFF_B2 + HH*4)          // 148736 B

#define MFMA(a,b,c) __builtin_amdgcn_mfma_f32_32x32x16_bf16(a,b,c,0,0,0)

// cheap bf16 pair pack: +0x8000 round + v_perm (3 VALU)
__device__ __forceinline__ u32 pack_bf2(float lo, float hi) {
    u32 ul, uh;
    __builtin_memcpy(&ul, &lo, 4);
    __builtin_memcpy(&uh, &hi, 4);
    return __builtin_amdgcn_perm(uh + 0x8000u, ul + 0x8000u, 0x07060302u);
}
__device__ __forceinline__ short f2bfs(float v) {
    __hip_bfloat16 h = __float2bfloat16(v);
    short r; __builtin_memcpy(&r, &h, 2); return r;
}
__device__ __forceinline__ f32x2 unpk2(u32 w) {
    u32 lo = w << 16;
    u32 hi2 = w & 0xffff0000u;
    float flo, fhi;
    __builtin_memcpy(&flo, &lo, 4);
    __builtin_memcpy(&fhi, &hi2, 4);
    return (f32x2){flo, fhi};
}
// tanh-form GELU on a pair (packed v_pk_* for the polynomial part)
__device__ __forceinline__ f32x2 gelu2(f32x2 x) {
    f32x2 x2 = x * x;
    f32x2 t = x * (x2 * 0.10294828f + 2.30220913f);
    f32x2 e;
    e.x = exp2f(t.x);
    e.y = exp2f(t.y);
    f32x2 ep = e + 1.0f;
    f32x2 r;
    r.x = __builtin_amdgcn_rcpf(ep.x);
    r.y = __builtin_amdgcn_rcpf(ep.y);
    return x - x * r;
}

union frag { bf16x8 v; u32 w[4]; };

// layer-1 C tile (ACC) -> gelu+bias -> bf16 pairs -> F2[2MT],F2[2MT+1]
// via v_permlane32_swap_b32 (VALU, dual-output) instead of ds_bpermute+selects:
// a=pk8[q0] (all lanes), b=pk8[q0+2]; after swap a'={a.lo,b.lo}=w[rr],
// b'={a.hi,b.hi}=w[rr+2]  (mapping verified against the r2-verified shuffle).
#define TRANS_MT_PL(ACC, MT) do {                                               \
    u32 pk8[8];                                                                 \
    _Pragma("unroll") for (int q = 0; q < 8; ++q) {                             \
        int row0 = 8 * (q >> 1) + 2 * (q & 1) + 4 * hi;                         \
        f32x2 bb = *(const f32x2*)(s_b1f + (MT) * 32 + row0);                   \
        f32x2 av = {ACC[2*q], ACC[2*q+1]};                                      \
        f32x2 hv = gelu2(av + bb);                                              \
        pk8[q] = pack_bf2(hv.x, hv.y);                                          \
    }                                                                           \
    _Pragma("unroll") for (int e = 0; e < 2; ++e) {                             \
        const int ks_ = 2 * (MT) + e;                                           \
        _Pragma("unroll") for (int rr = 0; rr < 2; ++rr) {                      \
            u32 a_ = pk8[rr + 4*e], b_ = pk8[rr + 4*e + 2];                     \
            asm("v_permlane32_swap_b32 %0, %1" : "+v"(a_), "+v"(b_));           \
            F2[ks_].w[rr] = a_; F2[ks_].w[rr + 2] = b_;                         \
        }                                                                       \
    }                                                                           \
} while (0)

// ---------------------------------------------------------------------------
// Kernel W0: transpose W0[0:256] to bf16 [feat][k] (k contiguous) for
// vectorized precompute loads (replaces 8 scalar stride-512B loads with 1 b128)
// ---------------------------------------------------------------------------
__global__ __launch_bounds__(256) void prep_w0_kernel(
    const float* __restrict__ W0, short* __restrict__ W0t)
{
    int e = blockIdx.x * 256 + threadIdx.x;   // 0..32767
    if (e >= HH * 256) return;
    int feat = e >> 8;
    int k = e & 255;
    W0t[feat * 256 + k] = f2bfs(W0[(size_t)k * HH + feat]);
}

// ---------------------------------------------------------------------------
// Kernel A: Ysrc = bf16((enc*mask) @ W0[0:128]), Yself = bf16(.. @ W0[128:256] + b0)
// ---------------------------------------------------------------------------
__global__ __launch_bounds__(128) void precompute_kernel(
    const float* __restrict__ enc, const float* __restrict__ mask,
    const short* __restrict__ W0t, const float* __restrict__ b0,
    __hip_bfloat16* __restrict__ Ysrc, __hip_bfloat16* __restrict__ Yself)
{
    const int tid = threadIdx.x;
    const int wave = tid >> 6;
    const int lane = tid & 63;
    const int li = lane & 31;
    const int hi = lane >> 5;
    const int rowBase = blockIdx.x * 64 + wave * 32;
    const int myrow = rowBase + li;

    const float m = mask[myrow];
    bf16x8 A[8];
    #pragma unroll
    for (int ks = 0; ks < 8; ++ks) {
        const float* p = enc + (size_t)myrow * HH + ks * 16 + hi * 8;
        float4 a = *(const float4*)p;
        float4 c = *(const float4*)(p + 4);
        frag f;
        f.w[0] = pack_bf2(a.x * m, a.y * m);
        f.w[1] = pack_bf2(a.z * m, a.w * m);
        f.w[2] = pack_bf2(c.x * m, c.y * m);
        f.w[3] = pack_bf2(c.z * m, c.w * m);
        A[ks] = f.v;
    }

    #pragma unroll
    for (int h2 = 0; h2 < 2; ++h2) {
        __hip_bfloat16* dest = h2 ? Yself : Ysrc;
        #pragma unroll 1
        for (int mt = 0; mt < 4; ++mt) {
            const float bias = h2 ? b0[mt * 32 + li] : 0.0f;
            f32x16 acc;
            #pragma unroll
            for (int r = 0; r < 16; ++r) acc[r] = 0.f;
            #pragma unroll
            for (int ks = 0; ks < 8; ++ks) {
                bf16x8 Bf = *(const bf16x8*)(W0t + (size_t)(mt * 32 + li) * 256
                                              + h2 * HH + ks * 16 + hi * 8);
                acc = MFMA(A[ks], Bf, acc);
            }
            #pragma unroll
            for (int r = 0; r < 16; ++r) {
                int rrow = (r & 3) + 8 * (r >> 2) + 4 * hi;
                dest[(size_t)(rowBase + rrow) * HH + mt * 32 + li] =
                    __float2bfloat16(acc[r] + bias);
            }
        }
    }
}

// ---------------------------------------------------------------------------
// Kernel B: per-edge MLP + masked mean + fused per-block stats partials.
// r13/r14 no-spill structure; mt=0 of layer-1 streamed inside layer-0
// (uses fresh h regs, skips 8 H0 re-reads, hides write->read latency);
// F2 transition via v_permlane32_swap_b32.
// ---------------------------------------------------------------------------
__global__ __launch_bounds__(THREADS) void mpnn_kernel(
    const float* __restrict__ enc, const float* __restrict__ mask,
    const float* __restrict__ dist, const int* __restrict__ eidx,
    const __hip_bfloat16* __restrict__ Ysrc, const __hip_bfloat16* __restrict__ Yself,
    const float* __restrict__ W0,
    const float* __restrict__ W1, const float* __restrict__ b1,
    const float* __restrict__ W2, const float* __restrict__ b2,
    float* __restrict__ upd, float* __restrict__ psum2, float* __restrict__ psumsq2)
{
    extern __shared__ char lds[];
    const int tid  = threadIdx.x;
    const int wave = tid >> 6;
    const int lane = tid & 63;
    const int li   = lane & 31;
    const int hi   = lane >> 5;
    const int nodeBase = blockIdx.x * NPB;

    // ---- stage W1/W2 fragment tables (bf16, MFMA frag layout) ----
    #pragma unroll
    for (int tbl = 0; tbl < 2; ++tbl) {
        const float* W = tbl ? W2 : W1;
        short* dst = (short*)(lds + tbl * 32768);
        #pragma unroll
        for (int i = 0; i < (HH * HH) / THREADS; ++i) {
            int e = i * THREADS + tid;
            int feat = e & 127, k = e >> 7;
            float v = W[(size_t)k * HH + feat];
            int mt = feat >> 5, ks = k >> 4, h2 = (k >> 3) & 1, j = k & 7;
            dst[((mt * 8 + ks) * 64 + h2 * 32 + (feat & 31)) * 8 + j] = f2bfs(v);
        }
    }
    {
        uint4* sv = (uint4*)(lds + OFF_SELF);
        sv[tid]       = *(const uint4*)(Yself + (size_t)nodeBase * HH + tid * 8);
        sv[tid + 512] = *(const uint4*)(Yself + (size_t)nodeBase * HH + (tid + 512) * 8);
    }
    short* swd = (short*)(lds + OFF_WD);
    if (tid < HH) swd[tid] = f2bfs(W0[(size_t)256 * HH + tid]);
    float* s_b1f = (float*)(lds + OFF_B1);
    if (tid < HH) s_b1f[tid] = b1[tid];
    float* s_b2f = (float*)(lds + OFF_B2);
    if (tid < HH) s_b2f[tid] = b2[tid];
    __syncthreads();

    const int b = nodeBase >> 12;
    const __hip_bfloat16* YsB = Ysrc + (size_t)b * NN * HH;
    char* h0buf = lds + OFF_H0 + (size_t)wave * 8 * 64 * 16;

    float st_s0 = 0.f, st_q0 = 0.f, st_s1 = 0.f, st_q1 = 0.f;

    // ---- prologue: gather + meta for first node ----
    const int node0 = wave * NPI;
    int   ie = eidx[(size_t)(nodeBase + node0) * KK + li];
    float dd = dist[(size_t)(nodeBase + node0) * KK + li];
    float mk = mask[nodeBase + node0];
    bf16x8 g[8];
    {
        int ic0 = ie < 0 ? 0 : ie;
        const char* gb = (const char*)(YsB + (size_t)ic0 * HH) + hi * 16;
        #pragma unroll
        for (int ks = 0; ks < 8; ++ks) g[ks] = *(const bf16x8*)(gb + ks * 32);
    }

    #pragma unroll 1
    for (int i = 0; i < NPI; ++i) {
        const int node_local = node0 + i;
        const int gnode = nodeBase + node_local;

        bool valid = ie >= 0;
        u32 vmask = (u32)__ballot(valid);
        int vc = __popc(vmask);
        float inv_vc = 1.0f / (float)(vc < 1 ? 1 : vc);
        float dste = dd;
        float mask_n = mk;

        // ---- layer 0 + streamed mt=0 of layer 1: h -> LDS AND a0 MFMA ----
        const short* sself = (const short*)(lds + OFF_SELF) + node_local * HH;
        const f32x2 d2 = {dste, dste};
        f32x16 a0;
        #pragma unroll
        for (int r = 0; r < 16; ++r) a0[r] = 0.f;
        #pragma unroll
        for (int ks = 0; ks < 8; ++ks) {
            frag gg; gg.v = g[ks];
            frag yy; yy.v = *(const bf16x8*)(sself + ks * 16 + hi * 8);
            frag dw; dw.v = *(const bf16x8*)(swd + ks * 16 + hi * 8);
            frag h;
            #pragma unroll
            for (int q = 0; q < 4; ++q) {
                f32x2 z = unpk2(gg.w[q]) + unpk2(yy.w[q]) + d2 * unpk2(dw.w[q]);
                f32x2 hv = gelu2(z);
                h.w[q] = pack_bf2(hv.x, hv.y);
            }
            *(bf16x8*)(h0buf + (ks * 64 + lane) * 16) = h.v;
            a0 = MFMA(*(const bf16x8*)(lds + OFF_W1 + ((0 * 8 + ks) * 64 + lane) * 16),
                      h.v, a0);
        }

        // ---- prefetch next node's gather + meta (hides under layers 1-2) ----
        if (i + 1 < NPI) {
            ie = eidx[(size_t)(gnode + 1) * KK + li];
            dd = dist[(size_t)(gnode + 1) * KK + li];
            mk = mask[gnode + 1];
            int icn = ie < 0 ? 0 : ie;
            const char* gb = (const char*)(YsB + (size_t)icn * HH) + hi * 16;
            #pragma unroll
            for (int ks = 0; ks < 8; ++ks) g[ks] = *(const bf16x8*)(gb + ks * 32);
        }

        // ---- finish layer 1: TRANS mt=0 from a0, then mt=1..3 from LDS ----
        frag F2[8];
        TRANS_MT_PL(a0, 0);
        #pragma unroll
        for (int mt = 1; mt < 4; ++mt) {
            f32x16 acc;
            #pragma unroll
            for (int r = 0; r < 16; ++r) acc[r] = 0.f;
            #pragma unroll
            for (int ks = 0; ks < 8; ++ks) {
                bf16x8 a = *(const bf16x8*)(lds + OFF_W1 + ((mt * 8 + ks) * 64 + lane) * 16);
                bf16x8 h0 = *(const bf16x8*)(h0buf + (ks * 64 + lane) * 16);
                acc = MFMA(a, h0, acc);
            }
            TRANS_MT_PL(acc, mt);
        }

        // ---- layer 2 (normal), one nt-tile at a time -> scalars ----
        float s0, s1, s2, s3;
        #pragma unroll
        for (int nt = 0; nt < 4; ++nt) {
            f32x16 acc;
            #pragma unroll
            for (int r = 0; r < 16; ++r) acc[r] = 0.f;
            #pragma unroll
            for (int ks = 0; ks < 8; ++ks) {
                bf16x8 w2f = *(const bf16x8*)(lds + OFF_W2 + ((nt * 8 + ks) * 64 + lane) * 16);
                acc = MFMA(F2[ks].v, w2f, acc);
            }
            float bv = s_b2f[nt * 32 + li];
            const f32x2 bv2 = {bv, bv};
            float t = 0.f;
            #pragma unroll
            for (int q = 0; q < 8; ++q) {
                f32x2 av = {acc[2*q], acc[2*q+1]};
                f32x2 v2 = gelu2(av + bv2);
                int r0 = 2*q, r1 = 2*q + 1;
                int e0 = (r0 & 3) + 8 * (r0 >> 2) + 4 * hi;
                int e1 = (r1 & 3) + 8 * (r1 >> 2) + 4 * hi;
                t += ((vmask >> e0) & 1) ? v2.x : 0.f;
                t += ((vmask >> e1) & 1) ? v2.y : 0.f;
            }
            t += __shfl_xor(t, 32, 64);
            if (nt == 0) s0 = t; else if (nt == 1) s1 = t;
            else if (nt == 2) s2 = t; else s3 = t;
        }

        // ---- epilogue ----
        float sa = hi ? s2 : s0;
        float sb = hi ? s3 : s1;
        int f0 = (hi * 2) * 32 + li;
        int f1 = (hi * 2 + 1) * 32 + li;
        float u0 = (enc[(size_t)gnode * HH + f0] + sa * inv_vc) * mask_n;
        float u1 = (enc[(size_t)gnode * HH + f1] + sb * inv_vc) * mask_n;
        upd[(size_t)gnode * HH + f0] = u0;
        upd[(size_t)gnode * HH + f1] = u1;
        st_s0 += u0; st_q0 = fmaf(u0, u0, st_q0);
        st_s1 += u1; st_q1 = fmaf(u1, u1, st_q1);
    }

    // ---- fused stats: block-level partials per feature ----
    __syncthreads();
    float4* red = (float4*)(lds + OFF_H0);
    red[tid] = make_float4(st_s0, st_q0, st_s1, st_q1);
    __syncthreads();
    if (tid < HH) {
        const int f = tid;
        const int q = f >> 5;
        const int rl = (q >> 1) * 32 + (f & 31);
        const bool use1 = (q & 1) != 0;
        float s = 0.f, sq = 0.f;
        #pragma unroll
        for (int w = 0; w < 8; ++w) {
            float4 v = red[w * 64 + rl];
            s  += use1 ? v.z : v.x;
            sq += use1 ? v.w : v.y;
        }
        psum2[(size_t)blockIdx.x * HH + f]   = s;
        psumsq2[(size_t)blockIdx.x * HH + f] = sq;
    }
}

// ---------------------------------------------------------------------------
// Kernel 2b: combine per-block partials -> mean, 1/std per (b, feature)
// ---------------------------------------------------------------------------
__global__ __launch_bounds__(128) void finalize_stats_kernel(
    const float* __restrict__ psum2, const float* __restrict__ psumsq2,
    const float* __restrict__ mask, float* __restrict__ meanp, float* __restrict__ istdp)
{
    const int b = blockIdx.x;
    const int j = threadIdx.x;
    float s = 0.f, s2 = 0.f;
    #pragma unroll 4
    for (int c = 0; c < BPB; ++c) {
        s  += psum2[((size_t)(b * BPB + c)) * HH + j];
        s2 += psumsq2[((size_t)(b * BPB + c)) * HH + j];
    }
    float cpart = 0.f;
    #pragma unroll 4
    for (int t = 0; t < NN / HH; ++t)
        cpart += mask[(size_t)b * NN + (size_t)t * HH + j];
    __shared__ float red[HH];
    red[j] = cpart;
    __syncthreads();
    for (int off = HH / 2; off > 0; off >>= 1) {
        if (j < off) red[j] += red[j + off];
        __syncthreads();
    }
    float counts = red[0];
    if (counts == 0.f) counts = 1.f;
    float mean = s / counts;
    float var  = (s2 - 2.f * mean * s + (float)NN * mean * mean) / counts;
    meanp[b * HH + j] = mean;
    istdp[b * HH + j] = 1.0f / sqrtf(var + 1e-5f);
}

// ---------------------------------------------------------------------------
// Kernel 3: normalize out0 in place + write pass-through outputs
// ---------------------------------------------------------------------------
__global__ void write_out_kernel(
    const float* __restrict__ mask, const float* __restrict__ dist,
    const int* __restrict__ eidx, const float* __restrict__ meanp,
    const float* __restrict__ istdp, const float* __restrict__ scale,
    const float* __restrict__ shift, float* __restrict__ out)
{
    const size_t T0 = (size_t)BB * NN * HH;
    const size_t T1 = (size_t)BB * NN;
    const size_t T2 = (size_t)BB * NN * KK;
    const size_t stride = (size_t)gridDim.x * blockDim.x;
    const size_t t = (size_t)blockIdx.x * blockDim.x + threadIdx.x;

    for (size_t x = t; x < T0; x += stride) {
        int h = (int)(x & (HH - 1));
        size_t bn = x >> 7;
        int b = (int)(bn >> 12);
        float m = mask[bn];
        float v = (out[x] - meanp[b * HH + h]) * istdp[b * HH + h] * scale[h] + shift[h];
        out[x] = v * m;
    }
    float* out1 = out + T0;
    for (size_t x = t; x < T1; x += stride) out1[x] = mask[x];
    float* out2 = out1 + T1;
    for (size_t x = t; x < T2; x += stride) out2[x] = dist[x];
    float* out3 = out2 + T2;
    for (size_t x = t; x < T2; x += stride) out3[x] = (float)eidx[x];
}

// ---------------------------------------------------------------------------
extern "C" void kernel_launch(void* const* d_in, const int* in_sizes, int n_in,
                              void* d_out, int out_size, void* d_ws, size_t ws_size,
                              hipStream_t stream) {
    const float* enc   = (const float*)d_in[0];
    const float* mask  = (const float*)d_in[1];
    const float* dist  = (const float*)d_in[2];
    const int*   eidx  = (const int*)  d_in[3];
    const float* W0    = (const float*)d_in[4];
    const float* b0    = (const float*)d_in[5];
    const float* W1    = (const float*)d_in[6];
    const float* b1    = (const float*)d_in[7];
    const float* W2    = (const float*)d_in[8];
    const float* b2    = (const float*)d_in[9];
    const float* scale = (const float*)d_in[10];
    const float* shift = (const float*)d_in[11];
    float* out = (float*)d_out;
    float* upd = out;   // pre-norm upd lives in out[0:B*N*H], normalized in place later

    const size_t T0 = (size_t)BB * NN * HH;
    const size_t T1 = (size_t)BB * NN;

    __hip_bfloat16* Ysrc  = (__hip_bfloat16*)d_ws;                 // 4 MB
    __hip_bfloat16* Yself = (__hip_bfloat16*)(out + T0 + T1);      // 4 MB (out2/out3 region, overwritten last)
    float* wsf     = (float*)((char*)d_ws + (size_t)BB * NN * HH * 2);
    float* psum2   = wsf;                                          // 128 KB
    float* psumsq2 = psum2 + (size_t)NBLK * HH;                    // 128 KB
    float* meanp   = psumsq2 + (size_t)NBLK * HH;
    float* istdp   = meanp + (size_t)BB * HH;
    short* W0t     = (short*)(istdp + (size_t)BB * HH);            // 64 KB

    hipFuncSetAttribute((const void*)mpnn_kernel,
                        hipFuncAttributeMaxDynamicSharedMemorySize, LDS_TOTAL);

    prep_w0_kernel<<<dim3(128), dim3(256), 0, stream>>>(W0, W0t);
    precompute_kernel<<<dim3(256), dim3(128), 0, stream>>>(enc, mask, W0t, b0, Ysrc, Yself);
    mpnn_kernel<<<dim3(NBLK), dim3(THREADS), LDS_TOTAL, stream>>>(
        enc, mask, dist, eidx, Ysrc, Yself, W0, W1, b1, W2, b2, upd, psum2, psumsq2);
    finalize_stats_kernel<<<dim3(BB), dim3(128), 0, stream>>>(psum2, psumsq2, mask, meanp, istdp);
    write_out_kernel<<<dim3(1024), dim3(256), 0, stream>>>(
        mask, dist, eidx, meanp, istdp, scale, shift, out);
}

// Round 17
// 149.987 us; speedup vs baseline: 1.1053x; 1.0430x over previous
//
#include <hip/hip_runtime.h>
#include <hip/hip_bf16.h>
#include <math.h>

#define BB 4
#define NN 4096
#define KK 32
#define HH 128

#define NPB 64         // nodes per block -> grid 256 = exactly 1 block/CU
#define THREADS 1024   // 16 waves = 4 waves/SIMD (2x r16's TLP)
#define NPAIR 8        // wave pairs per block; each pair owns 8 nodes
#define NPI (NPB / NPAIR)
#define NBLK ((BB * NN) / NPB)       // 256 blocks
#define BPB (NBLK / BB)              // 64 blocks per batch

typedef short bf16x8 __attribute__((ext_vector_type(8)));
typedef float f32x16 __attribute__((ext_vector_type(16)));
typedef float f32x2  __attribute__((ext_vector_type(2)));
typedef unsigned int u32;

// LDS map (145.25 KB, 1 block/CU — but now 16 waves/block):
// H0/F2 buffer is per wave-PAIR (8 pairs x 8 KB), shared via barriers.
#define OFF_W1   0
#define OFF_W2   32768
#define OFF_H0   65536                     // 8 pairs x 8 ks x 64 lanes x 16 B
#define OFF_SELF (OFF_H0 + 65536)          // 64 nodes x 128 bf16 = 16384 B
#define OFF_WD   (OFF_SELF + NPB*HH*2)     // 256 B
#define OFF_B1   (OFF_WD + HH*2)           // 512 B (f32 b1)
#define OFF_B2   (OFF_B1 + HH*4)           // 512 B (f32 b2)
#define LDS_TOTAL (OFF_B2 + HH*4)          // 148736 B

#define MFMA(a,b,c) __builtin_amdgcn_mfma_f32_32x32x16_bf16(a,b,c,0,0,0)

// cheap bf16 pair pack: +0x8000 round + v_perm (3 VALU)
__device__ __forceinline__ u32 pack_bf2(float lo, float hi) {
    u32 ul, uh;
    __builtin_memcpy(&ul, &lo, 4);
    __builtin_memcpy(&uh, &hi, 4);
    return __builtin_amdgcn_perm(uh + 0x8000u, ul + 0x8000u, 0x07060302u);
}
__device__ __forceinline__ short f2bfs(float v) {
    __hip_bfloat16 h = __float2bfloat16(v);
    short r; __builtin_memcpy(&r, &h, 2); return r;
}
__device__ __forceinline__ f32x2 unpk2(u32 w) {
    u32 lo = w << 16;
    u32 hi2 = w & 0xffff0000u;
    float flo, fhi;
    __builtin_memcpy(&flo, &lo, 4);
    __builtin_memcpy(&fhi, &hi2, 4);
    return (f32x2){flo, fhi};
}
// tanh-form GELU on a pair (packed v_pk_* for the polynomial part)
__device__ __forceinline__ f32x2 gelu2(f32x2 x) {
    f32x2 x2 = x * x;
    f32x2 t = x * (x2 * 0.10294828f + 2.30220913f);
    f32x2 e;
    e.x = exp2f(t.x);
    e.y = exp2f(t.y);
    f32x2 ep = e + 1.0f;
    f32x2 r;
    r.x = __builtin_amdgcn_rcpf(ep.x);
    r.y = __builtin_amdgcn_rcpf(ep.y);
    return x - x * r;
}

union frag { bf16x8 v; u32 w[4]; };

// layer-1 C tile (ACC, global tile index MT) -> gelu+bias -> bf16 pairs ->
// FARR[LB], FARR[LB+1] via v_permlane32_swap_b32 (mapping verified r15/r16).
#define TRANS_MT_PL(ACC, MT, FARR, LB) do {                                     \
    u32 pk8[8];                                                                 \
    _Pragma("unroll") for (int q = 0; q < 8; ++q) {                             \
        int row0 = 8 * (q >> 1) + 2 * (q & 1) + 4 * hi;                         \
        f32x2 bb = *(const f32x2*)(s_b1f + (MT) * 32 + row0);                   \
        f32x2 av = {ACC[2*q], ACC[2*q+1]};                                      \
        f32x2 hv = gelu2(av + bb);                                              \
        pk8[q] = pack_bf2(hv.x, hv.y);                                          \
    }                                                                           \
    _Pragma("unroll") for (int e = 0; e < 2; ++e) {                             \
        _Pragma("unroll") for (int rr = 0; rr < 2; ++rr) {                      \
            u32 a_ = pk8[rr + 4*e], b_ = pk8[rr + 4*e + 2];                     \
            asm("v_permlane32_swap_b32 %0, %1" : "+v"(a_), "+v"(b_));           \
            FARR[(LB) + e].w[rr] = a_; FARR[(LB) + e].w[rr + 2] = b_;           \
        }                                                                       \
    }                                                                           \
} while (0)

// ---------------------------------------------------------------------------
// Kernel W0: transpose W0[0:256] to bf16 [feat][k] for vectorized precompute
// ---------------------------------------------------------------------------
__global__ __launch_bounds__(256) void prep_w0_kernel(
    const float* __restrict__ W0, short* __restrict__ W0t)
{
    int e = blockIdx.x * 256 + threadIdx.x;
    if (e >= HH * 256) return;
    int feat = e >> 8;
    int k = e & 255;
    W0t[feat * 256 + k] = f2bfs(W0[(size_t)k * HH + feat]);
}

// ---------------------------------------------------------------------------
// Kernel A: Ysrc = bf16((enc*mask) @ W0[0:128]), Yself = bf16(.. @ W0[128:256] + b0)
// ---------------------------------------------------------------------------
__global__ __launch_bounds__(128) void precompute_kernel(
    const float* __restrict__ enc, const float* __restrict__ mask,
    const short* __restrict__ W0t, const float* __restrict__ b0,
    __hip_bfloat16* __restrict__ Ysrc, __hip_bfloat16* __restrict__ Yself)
{
    const int tid = threadIdx.x;
    const int wave = tid >> 6;
    const int lane = tid & 63;
    const int li = lane & 31;
    const int hi = lane >> 5;
    const int rowBase = blockIdx.x * 64 + wave * 32;
    const int myrow = rowBase + li;

    const float m = mask[myrow];
    bf16x8 A[8];
    #pragma unroll
    for (int ks = 0; ks < 8; ++ks) {
        const float* p = enc + (size_t)myrow * HH + ks * 16 + hi * 8;
        float4 a = *(const float4*)p;
        float4 c = *(const float4*)(p + 4);
        frag f;
        f.w[0] = pack_bf2(a.x * m, a.y * m);
        f.w[1] = pack_bf2(a.z * m, a.w * m);
        f.w[2] = pack_bf2(c.x * m, c.y * m);
        f.w[3] = pack_bf2(c.z * m, c.w * m);
        A[ks] = f.v;
    }

    #pragma unroll
    for (int h2 = 0; h2 < 2; ++h2) {
        __hip_bfloat16* dest = h2 ? Yself : Ysrc;
        #pragma unroll 1
        for (int mt = 0; mt < 4; ++mt) {
            const float bias = h2 ? b0[mt * 32 + li] : 0.0f;
            f32x16 acc;
            #pragma unroll
            for (int r = 0; r < 16; ++r) acc[r] = 0.f;
            #pragma unroll
            for (int ks = 0; ks < 8; ++ks) {
                bf16x8 Bf = *(const bf16x8*)(W0t + (size_t)(mt * 32 + li) * 256
                                              + h2 * HH + ks * 16 + hi * 8);
                acc = MFMA(A[ks], Bf, acc);
            }
            #pragma unroll
            for (int r = 0; r < 16; ++r) {
                int rrow = (r & 3) + 8 * (r >> 2) + 4 * hi;
                dest[(size_t)(rowBase + rrow) * HH + mt * 32 + li] =
                    __float2bfloat16(acc[r] + bias);
            }
        }
    }
}

// ---------------------------------------------------------------------------
// Kernel B: per-edge MLP + masked mean + fused stats. Wave-PAIR cooperation:
// pair shares one 8KB H0/F2 buffer; even wave does ks0-3/mt0-1/nt0-1 (feats
// 0-63), odd does ks4-7/mt2-3/nt2-3 (feats 64-127). 16 waves -> 4/SIMD.
// ---------------------------------------------------------------------------
__global__ __launch_bounds__(THREADS) void mpnn_kernel(
    const float* __restrict__ enc, const float* __restrict__ mask,
    const float* __restrict__ dist, const int* __restrict__ eidx,
    const __hip_bfloat16* __restrict__ Ysrc, const __hip_bfloat16* __restrict__ Yself,
    const float* __restrict__ W0,
    const float* __restrict__ W1, const float* __restrict__ b1,
    const float* __restrict__ W2, const float* __restrict__ b2,
    float* __restrict__ upd, float* __restrict__ psum2, float* __restrict__ psumsq2)
{
    extern __shared__ char lds[];
    const int tid  = threadIdx.x;
    const int wave = tid >> 6;
    const int lane = tid & 63;
    const int li   = lane & 31;
    const int hi   = lane >> 5;
    const int p    = wave & 1;    // pair parity
    const int pr   = wave >> 1;   // pair index 0..7
    const int nodeBase = blockIdx.x * NPB;

    // ---- stage W1/W2 fragment tables (bf16, MFMA frag layout) ----
    #pragma unroll
    for (int tbl = 0; tbl < 2; ++tbl) {
        const float* W = tbl ? W2 : W1;
        short* dst = (short*)(lds + tbl * 32768);
        #pragma unroll
        for (int i = 0; i < (HH * HH) / THREADS; ++i) {
            int e = i * THREADS + tid;
            int feat = e & 127, k = e >> 7;
            float v = W[(size_t)k * HH + feat];
            int mt = feat >> 5, ks = k >> 4, h2 = (k >> 3) & 1, j = k & 7;
            dst[((mt * 8 + ks) * 64 + h2 * 32 + (feat & 31)) * 8 + j] = f2bfs(v);
        }
    }
    {
        uint4* sv = (uint4*)(lds + OFF_SELF);
        sv[tid] = *(const uint4*)(Yself + (size_t)nodeBase * HH + tid * 8);
    }
    short* swd = (short*)(lds + OFF_WD);
    if (tid < HH) swd[tid] = f2bfs(W0[(size_t)256 * HH + tid]);
    float* s_b1f = (float*)(lds + OFF_B1);
    if (tid < HH) s_b1f[tid] = b1[tid];
    float* s_b2f = (float*)(lds + OFF_B2);
    if (tid < HH) s_b2f[tid] = b2[tid];
    __syncthreads();

    const int b = nodeBase >> 12;
    const __hip_bfloat16* YsB = Ysrc + (size_t)b * NN * HH;
    char* h0buf = lds + OFF_H0 + (size_t)pr * 8192;   // pair-shared H0/F2

    float st_s0 = 0.f, st_q0 = 0.f, st_s1 = 0.f, st_q1 = 0.f;

    #pragma unroll 1
    for (int i = 0; i < NPI; ++i) {
        __syncthreads();   // A: prior iter's F2 reads complete before overwrite

        const int node_local = pr * NPI + i;
        const int gnode = nodeBase + node_local;

        int ie = eidx[(size_t)gnode * KK + li];
        float dste = dist[(size_t)gnode * KK + li];
        float mask_n = mask[gnode];
        bool valid = ie >= 0;
        int ic = valid ? ie : 0;
        u32 vmask = (u32)__ballot(valid);
        int vc = __popc(vmask);
        float inv_vc = 1.0f / (float)(vc < 1 ? 1 : vc);

        // ---- layer 0 (my ks half): gather + add/gelu -> shared H0 ----
        const char* gbase = (const char*)(YsB + (size_t)ic * HH) + hi * 16;
        const short* sself = (const short*)(lds + OFF_SELF) + node_local * HH;
        const f32x2 d2 = {dste, dste};
        #pragma unroll
        for (int kk = 0; kk < 4; ++kk) {
            const int ks = p * 4 + kk;
            frag gg; gg.v = *(const bf16x8*)(gbase + ks * 32);
            frag yy; yy.v = *(const bf16x8*)(sself + ks * 16 + hi * 8);
            frag dw; dw.v = *(const bf16x8*)(swd + ks * 16 + hi * 8);
            frag h;
            #pragma unroll
            for (int q = 0; q < 4; ++q) {
                f32x2 z = unpk2(gg.w[q]) + unpk2(yy.w[q]) + d2 * unpk2(dw.w[q]);
                f32x2 hv = gelu2(z);
                h.w[q] = pack_bf2(hv.x, hv.y);
            }
            *(bf16x8*)(h0buf + (ks * 64 + lane) * 16) = h.v;
        }
        __syncthreads();   // B: full H0 ready

        // ---- layer 1 (my 2 mt tiles): read full H0, TRANS -> F2loc ----
        frag F2loc[4];
        #pragma unroll
        for (int j = 0; j < 2; ++j) {
            const int mt = 2 * p + j;
            f32x16 acc;
            #pragma unroll
            for (int r = 0; r < 16; ++r) acc[r] = 0.f;
            #pragma unroll
            for (int ks = 0; ks < 8; ++ks) {
                bf16x8 a = *(const bf16x8*)(lds + OFF_W1 + ((mt * 8 + ks) * 64 + lane) * 16);
                bf16x8 h0 = *(const bf16x8*)(h0buf + (ks * 64 + lane) * 16);
                acc = MFMA(a, h0, acc);
            }
            TRANS_MT_PL(acc, mt, F2loc, 2 * j);
        }
        __syncthreads();   // C: all H0 reads done -> safe to overwrite with F2

        #pragma unroll
        for (int s = 0; s < 4; ++s)
            *(bf16x8*)(h0buf + ((4 * p + s) * 64 + lane) * 16) = F2loc[s].v;
        __syncthreads();   // D: full F2 ready

        // ---- layer 2 (my 2 nt tiles): A-frag from shared F2 in LDS ----
        float sres[2];
        #pragma unroll
        for (int j = 0; j < 2; ++j) {
            const int nt = 2 * p + j;
            f32x16 acc;
            #pragma unroll
            for (int r = 0; r < 16; ++r) acc[r] = 0.f;
            #pragma unroll
            for (int ks = 0; ks < 8; ++ks) {
                bf16x8 f2f = *(const bf16x8*)(h0buf + (ks * 64 + lane) * 16);
                bf16x8 w2f = *(const bf16x8*)(lds + OFF_W2 + ((nt * 8 + ks) * 64 + lane) * 16);
                acc = MFMA(f2f, w2f, acc);
            }
            float bv = s_b2f[nt * 32 + li];
            const f32x2 bv2 = {bv, bv};
            float t = 0.f;
            #pragma unroll
            for (int q = 0; q < 8; ++q) {
                f32x2 av = {acc[2*q], acc[2*q+1]};
                f32x2 v2 = gelu2(av + bv2);
                int r0 = 2*q, r1 = 2*q + 1;
                int e0 = (r0 & 3) + 8 * (r0 >> 2) + 4 * hi;
                int e1 = (r1 & 3) + 8 * (r1 >> 2) + 4 * hi;
                t += ((vmask >> e0) & 1) ? v2.x : 0.f;
                t += ((vmask >> e1) & 1) ? v2.y : 0.f;
            }
            t += __shfl_xor(t, 32, 64);
            sres[j] = t;
        }

        // ---- epilogue: my feats are (2p)*32+li and (2p+1)*32+li ----
        int f0 = (2 * p) * 32 + li;
        int f1 = (2 * p + 1) * 32 + li;
        float u0 = (enc[(size_t)gnode * HH + f0] + sres[0] * inv_vc) * mask_n;
        float u1 = (enc[(size_t)gnode * HH + f1] + sres[1] * inv_vc) * mask_n;
        upd[(size_t)gnode * HH + f0] = u0;   // hi=0/1 lanes write same value
        upd[(size_t)gnode * HH + f1] = u1;
        if (hi == 0) {
            st_s0 += u0; st_q0 = fmaf(u0, u0, st_q0);
            st_s1 += u1; st_q1 = fmaf(u1, u1, st_q1);
        }
    }

    // ---- fused stats: block partials per feature (reuses H0 region) ----
    __syncthreads();
    float4* red = (float4*)(lds + OFF_H0);
    red[tid] = (hi == 0) ? make_float4(st_s0, st_q0, st_s1, st_q1)
                         : make_float4(0.f, 0.f, 0.f, 0.f);
    __syncthreads();
    if (tid < HH) {
        const int f = tid;
        const int fp = f >> 6;           // parity owning this feat
        const int fs = (f >> 5) & 1;     // slot (0: s0/q0, 1: s1/q1)
        const int fl = f & 31;           // lane (hi=0)
        float s = 0.f, sq = 0.f;
        #pragma unroll
        for (int w8 = 0; w8 < 8; ++w8) {
            float4 v = red[(2 * w8 + fp) * 64 + fl];
            s  += fs ? v.z : v.x;
            sq += fs ? v.w : v.y;
        }
        psum2[(size_t)blockIdx.x * HH + f]   = s;
        psumsq2[(size_t)blockIdx.x * HH + f] = sq;
    }
}

// ---------------------------------------------------------------------------
// Kernel 2b: combine per-block partials -> mean, 1/std per (b, feature)
// ---------------------------------------------------------------------------
__global__ __launch_bounds__(128) void finalize_stats_kernel(
    const float* __restrict__ psum2, const float* __restrict__ psumsq2,
    const float* __restrict__ mask, float* __restrict__ meanp, float* __restrict__ istdp)
{
    const int b = blockIdx.x;
    const int j = threadIdx.x;
    float s = 0.f, s2 = 0.f;
    #pragma unroll 4
    for (int c = 0; c < BPB; ++c) {
        s  += psum2[((size_t)(b * BPB + c)) * HH + j];
        s2 += psumsq2[((size_t)(b * BPB + c)) * HH + j];
    }
    float cpart = 0.f;
    #pragma unroll 4
    for (int t = 0; t < NN / HH; ++t)
        cpart += mask[(size_t)b * NN + (size_t)t * HH + j];
    __shared__ float red[HH];
    red[j] = cpart;
    __syncthreads();
    for (int off = HH / 2; off > 0; off >>= 1) {
        if (j < off) red[j] += red[j + off];
        __syncthreads();
    }
    float counts = red[0];
    if (counts == 0.f) counts = 1.f;
    float mean = s / counts;
    float var  = (s2 - 2.f * mean * s + (float)NN * mean * mean) / counts;
    meanp[b * HH + j] = mean;
    istdp[b * HH + j] = 1.0f / sqrtf(var + 1e-5f);
}

// ---------------------------------------------------------------------------
// Kernel 3: normalize out0 in place + write pass-through outputs
// ---------------------------------------------------------------------------
__global__ void write_out_kernel(
    const float* __restrict__ mask, const float* __restrict__ dist,
    const int* __restrict__ eidx, const float* __restrict__ meanp,
    const float* __restrict__ istdp, const float* __restrict__ scale,
    const float* __restrict__ shift, float* __restrict__ out)
{
    const size_t T0 = (size_t)BB * NN * HH;
    const size_t T1 = (size_t)BB * NN;
    const size_t T2 = (size_t)BB * NN * KK;
    const size_t stride = (size_t)gridDim.x * blockDim.x;
    const size_t t = (size_t)blockIdx.x * blockDim.x + threadIdx.x;

    for (size_t x = t; x < T0; x += stride) {
        int h = (int)(x & (HH - 1));
        size_t bn = x >> 7;
        int b = (int)(bn >> 12);
        float m = mask[bn];
        float v = (out[x] - meanp[b * HH + h]) * istdp[b * HH + h] * scale[h] + shift[h];
        out[x] = v * m;
    }
    float* out1 = out + T0;
    for (size_t x = t; x < T1; x += stride) out1[x] = mask[x];
    float* out2 = out1 + T1;
    for (size_t x = t; x < T2; x += stride) out2[x] = dist[x];
    float* out3 = out2 + T2;
    for (size_t x = t; x < T2; x += stride) out3[x] = (float)eidx[x];
}

// ---------------------------------------------------------------------------
extern "C" void kernel_launch(void* const* d_in, const int* in_sizes, int n_in,
                              void* d_out, int out_size, void* d_ws, size_t ws_size,
                              hipStream_t stream) {
    const float* enc   = (const float*)d_in[0];
    const float* mask  = (const float*)d_in[1];
    const float* dist  = (const float*)d_in[2];
    const int*   eidx  = (const int*)  d_in[3];
    const float* W0    = (const float*)d_in[4];
    const float* b0    = (const float*)d_in[5];
    const float* W1    = (const float*)d_in[6];
    const float* b1    = (const float*)d_in[7];
    const float* W2    = (const float*)d_in[8];
    const float* b2    = (const float*)d_in[9];
    const float* scale = (const float*)d_in[10];
    const float* shift = (const float*)d_in[11];
    float* out = (float*)d_out;
    float* upd = out;   // pre-norm upd lives in out[0:B*N*H], normalized in place later

    const size_t T0 = (size_t)BB * NN * HH;
    const size_t T1 = (size_t)BB * NN;

    __hip_bfloat16* Ysrc  = (__hip_bfloat16*)d_ws;                 // 4 MB
    __hip_bfloat16* Yself = (__hip_bfloat16*)(out + T0 + T1);      // 4 MB (out2/out3 region, overwritten last)
    float* wsf     = (float*)((char*)d_ws + (size_t)BB * NN * HH * 2);
    float* psum2   = wsf;                                          // 128 KB
    float* psumsq2 = psum2 + (size_t)NBLK * HH;                    // 128 KB
    float* meanp   = psumsq2 + (size_t)NBLK * HH;
    float* istdp   = meanp + (size_t)BB * HH;
    short* W0t     = (short*)(istdp + (size_t)BB * HH);            // 64 KB

    hipFuncSetAttribute((const void*)mpnn_kernel,
                        hipFuncAttributeMaxDynamicSharedMemorySize, LDS_TOTAL);

    prep_w0_kernel<<<dim3(128), dim3(256), 0, stream>>>(W0, W0t);
    precompute_kernel<<<dim3(256), dim3(128), 0, stream>>>(enc, mask, W0t, b0, Ysrc, Yself);
    mpnn_kernel<<<dim3(NBLK), dim3(THREADS), LDS_TOTAL, stream>>>(
        enc, mask, dist, eidx, Ysrc, Yself, W0, W1, b1, W2, b2, upd, psum2, psumsq2);
    finalize_stats_kernel<<<dim3(BB), dim3(128), 0, stream>>>(psum2, psumsq2, mask, meanp, istdp);
    write_out_kernel<<<dim3(1024), dim3(256), 0, stream>>>(
        mask, dist, eidx, meanp, istdp, scale, shift, out);
}

// Round 18
// 123.872 us; speedup vs baseline: 1.3384x; 1.2108x over previous
//
#include <hip/hip_runtime.h>
#include <hip/hip_bf16.h>
#include <math.h>

#define BB 4
#define NN 4096
#define KK 32
#define HH 128

#define NPB 64         // nodes per block -> grid 256 = exactly 1 block/CU
#define THREADS 1024   // 16 waves = 4 waves/SIMD
#define NPAIR 8        // wave pairs per block; each pair owns 8 nodes
#define NPI (NPB / NPAIR)
#define NBLK ((BB * NN) / NPB)       // 256 blocks
#define BPB (NBLK / BB)              // 64 blocks per batch

typedef short bf16x8 __attribute__((ext_vector_type(8)));
typedef float f32x16 __attribute__((ext_vector_type(16)));
typedef float f32x2  __attribute__((ext_vector_type(2)));
typedef unsigned int u32;

// LDS map (145.25 KB, 1 block/CU, 16 waves). H0/F2 per wave-PAIR (8x8KB).
#define OFF_W1   0
#define OFF_W2   32768
#define OFF_H0   65536
#define OFF_SELF (OFF_H0 + 65536)          // 64 nodes x 128 bf16
#define OFF_WD   (OFF_SELF + NPB*HH*2)
#define OFF_B1   (OFF_WD + HH*2)
#define OFF_B2   (OFF_B1 + HH*4)
#define LDS_TOTAL (OFF_B2 + HH*4)          // 148736 B

#define MFMA(a,b,c) __builtin_amdgcn_mfma_f32_32x32x16_bf16(a,b,c,0,0,0)

// cheap bf16 pair pack: +0x8000 round + v_perm (3 VALU)
__device__ __forceinline__ u32 pack_bf2(float lo, float hi) {
    u32 ul, uh;
    __builtin_memcpy(&ul, &lo, 4);
    __builtin_memcpy(&uh, &hi, 4);
    return __builtin_amdgcn_perm(uh + 0x8000u, ul + 0x8000u, 0x07060302u);
}
__device__ __forceinline__ short f2bfs(float v) {
    __hip_bfloat16 h = __float2bfloat16(v);
    short r; __builtin_memcpy(&r, &h, 2); return r;
}
__device__ __forceinline__ f32x2 unpk2(u32 w) {
    u32 lo = w << 16;
    u32 hi2 = w & 0xffff0000u;
    float flo, fhi;
    __builtin_memcpy(&flo, &lo, 4);
    __builtin_memcpy(&fhi, &hi2, 4);
    return (f32x2){flo, fhi};
}
// tanh-form GELU on a pair. exp2 via raw v_exp_f32 (libm exp2f adds ~5-slot
// denorm fixup; raw is safe here: t<-126 -> 0 -> gelu=0; t>+128 -> inf ->
// rcp->0 -> gelu=x — both correct limits).
__device__ __forceinline__ f32x2 gelu2(f32x2 x) {
    f32x2 x2 = x * x;
    f32x2 t = x * (x2 * 0.10294828f + 2.30220913f);
    f32x2 e;
    e.x = __builtin_amdgcn_exp2f(t.x);
    e.y = __builtin_amdgcn_exp2f(t.y);
    f32x2 ep = e + 1.0f;
    f32x2 r;
    r.x = __builtin_amdgcn_rcpf(ep.x);
    r.y = __builtin_amdgcn_rcpf(ep.y);
    return x - x * r;
}

union frag { bf16x8 v; u32 w[4]; };

// layer-1 C tile (ACC, global tile MT) -> gelu+bias -> bf16 pairs ->
// FARR[LB], FARR[LB+1] via v_permlane32_swap_b32 (verified r15-r17).
#define TRANS_MT_PL(ACC, MT, FARR, LB) do {                                     \
    u32 pk8[8];                                                                 \
    _Pragma("unroll") for (int q = 0; q < 8; ++q) {                             \
        int row0 = 8 * (q >> 1) + 2 * (q & 1) + 4 * hi;                         \
        f32x2 bb = *(const f32x2*)(s_b1f + (MT) * 32 + row0);                   \
        f32x2 av = {ACC[2*q], ACC[2*q+1]};                                      \
        f32x2 hv = gelu2(av + bb);                                              \
        pk8[q] = pack_bf2(hv.x, hv.y);                                          \
    }                                                                           \
    _Pragma("unroll") for (int e = 0; e < 2; ++e) {                             \
        _Pragma("unroll") for (int rr = 0; rr < 2; ++rr) {                      \
            u32 a_ = pk8[rr + 4*e], b_ = pk8[rr + 4*e + 2];                     \
            asm("v_permlane32_swap_b32 %0, %1" : "+v"(a_), "+v"(b_));           \
            FARR[(LB) + e].w[rr] = a_; FARR[(LB) + e].w[rr + 2] = b_;           \
        }                                                                       \
    }                                                                           \
} while (0)

// ---------------------------------------------------------------------------
// Kernel W0: transpose W0[0:256] to bf16 [feat][k] for vectorized precompute
// ---------------------------------------------------------------------------
__global__ __launch_bounds__(256) void prep_w0_kernel(
    const float* __restrict__ W0, short* __restrict__ W0t)
{
    int e = blockIdx.x * 256 + threadIdx.x;
    if (e >= HH * 256) return;
    int feat = e >> 8;
    int k = e & 255;
    W0t[feat * 256 + k] = f2bfs(W0[(size_t)k * HH + feat]);
}

// ---------------------------------------------------------------------------
// Kernel A: Ysrc = bf16((enc*mask) @ W0[0:128]), Yself = bf16(.. @ W0[128:256] + b0)
// ---------------------------------------------------------------------------
__global__ __launch_bounds__(128) void precompute_kernel(
    const float* __restrict__ enc, const float* __restrict__ mask,
    const short* __restrict__ W0t, const float* __restrict__ b0,
    __hip_bfloat16* __restrict__ Ysrc, __hip_bfloat16* __restrict__ Yself)
{
    const int tid = threadIdx.x;
    const int wave = tid >> 6;
    const int lane = tid & 63;
    const int li = lane & 31;
    const int hi = lane >> 5;
    const int rowBase = blockIdx.x * 64 + wave * 32;
    const int myrow = rowBase + li;

    const float m = mask[myrow];
    bf16x8 A[8];
    #pragma unroll
    for (int ks = 0; ks < 8; ++ks) {
        const float* p = enc + (size_t)myrow * HH + ks * 16 + hi * 8;
        float4 a = *(const float4*)p;
        float4 c = *(const float4*)(p + 4);
        frag f;
        f.w[0] = pack_bf2(a.x * m, a.y * m);
        f.w[1] = pack_bf2(a.z * m, a.w * m);
        f.w[2] = pack_bf2(c.x * m, c.y * m);
        f.w[3] = pack_bf2(c.z * m, c.w * m);
        A[ks] = f.v;
    }

    #pragma unroll
    for (int h2 = 0; h2 < 2; ++h2) {
        __hip_bfloat16* dest = h2 ? Yself : Ysrc;
        #pragma unroll 1
        for (int mt = 0; mt < 4; ++mt) {
            const float bias = h2 ? b0[mt * 32 + li] : 0.0f;
            f32x16 acc;
            #pragma unroll
            for (int r = 0; r < 16; ++r) acc[r] = 0.f;
            #pragma unroll
            for (int ks = 0; ks < 8; ++ks) {
                bf16x8 Bf = *(const bf16x8*)(W0t + (size_t)(mt * 32 + li) * 256
                                              + h2 * HH + ks * 16 + hi * 8);
                acc = MFMA(A[ks], Bf, acc);
            }
            #pragma unroll
            for (int r = 0; r < 16; ++r) {
                int rrow = (r & 3) + 8 * (r >> 2) + 4 * hi;
                dest[(size_t)(rowBase + rrow) * HH + mt * 32 + li] =
                    __float2bfloat16(acc[r] + bias);
            }
        }
    }
}

// ---------------------------------------------------------------------------
// Kernel B: per-edge MLP + masked mean + fused stats. Wave-pair cooperation
// (r17 structure) + raw-exp2 GELU + precomputed float edge-mask (pk_fma
// accumulate replaces per-element bit-test/select in layer 2).
// ---------------------------------------------------------------------------
__global__ __launch_bounds__(THREADS) void mpnn_kernel(
    const float* __restrict__ enc, const float* __restrict__ mask,
    const float* __restrict__ dist, const int* __restrict__ eidx,
    const __hip_bfloat16* __restrict__ Ysrc, const __hip_bfloat16* __restrict__ Yself,
    const float* __restrict__ W0,
    const float* __restrict__ W1, const float* __restrict__ b1,
    const float* __restrict__ W2, const float* __restrict__ b2,
    float* __restrict__ upd, float* __restrict__ psum2, float* __restrict__ psumsq2)
{
    extern __shared__ char lds[];
    const int tid  = threadIdx.x;
    const int wave = tid >> 6;
    const int lane = tid & 63;
    const int li   = lane & 31;
    const int hi   = lane >> 5;
    const int p    = wave & 1;    // pair parity
    const int pr   = wave >> 1;   // pair index 0..7
    const int nodeBase = blockIdx.x * NPB;

    // ---- stage W1/W2 fragment tables (bf16, MFMA frag layout) ----
    #pragma unroll
    for (int tbl = 0; tbl < 2; ++tbl) {
        const float* W = tbl ? W2 : W1;
        short* dst = (short*)(lds + tbl * 32768);
        #pragma unroll
        for (int i = 0; i < (HH * HH) / THREADS; ++i) {
            int e = i * THREADS + tid;
            int feat = e & 127, k = e >> 7;
            float v = W[(size_t)k * HH + feat];
            int mt = feat >> 5, ks = k >> 4, h2 = (k >> 3) & 1, j = k & 7;
            dst[((mt * 8 + ks) * 64 + h2 * 32 + (feat & 31)) * 8 + j] = f2bfs(v);
        }
    }
    {
        uint4* sv = (uint4*)(lds + OFF_SELF);
        sv[tid] = *(const uint4*)(Yself + (size_t)nodeBase * HH + tid * 8);
    }
    short* swd = (short*)(lds + OFF_WD);
    if (tid < HH) swd[tid] = f2bfs(W0[(size_t)256 * HH + tid]);
    float* s_b1f = (float*)(lds + OFF_B1);
    if (tid < HH) s_b1f[tid] = b1[tid];
    float* s_b2f = (float*)(lds + OFF_B2);
    if (tid < HH) s_b2f[tid] = b2[tid];
    __syncthreads();

    const int b = nodeBase >> 12;
    const __hip_bfloat16* YsB = Ysrc + (size_t)b * NN * HH;
    char* h0buf = lds + OFF_H0 + (size_t)pr * 8192;   // pair-shared H0/F2

    float st_s0 = 0.f, st_q0 = 0.f, st_s1 = 0.f, st_q1 = 0.f;

    #pragma unroll 1
    for (int i = 0; i < NPI; ++i) {
        __syncthreads();   // A: prior iter's F2 reads complete before overwrite

        const int node_local = pr * NPI + i;
        const int gnode = nodeBase + node_local;

        int ie = eidx[(size_t)gnode * KK + li];
        float dste = dist[(size_t)gnode * KK + li];
        float mask_n = mask[gnode];
        bool valid = ie >= 0;
        int ic = valid ? ie : 0;
        u32 vmask = (u32)__ballot(valid);
        int vc = __popc(vmask);
        float inv_vc = 1.0f / (float)(vc < 1 ? 1 : vc);

        // ---- layer 0 (my ks half): gather + add/gelu -> shared H0 ----
        const char* gbase = (const char*)(YsB + (size_t)ic * HH) + hi * 16;
        const short* sself = (const short*)(lds + OFF_SELF) + node_local * HH;
        const f32x2 d2 = {dste, dste};
        #pragma unroll
        for (int kk = 0; kk < 4; ++kk) {
            const int ks = p * 4 + kk;
            frag gg; gg.v = *(const bf16x8*)(gbase + ks * 32);
            frag yy; yy.v = *(const bf16x8*)(sself + ks * 16 + hi * 8);
            frag dw; dw.v = *(const bf16x8*)(swd + ks * 16 + hi * 8);
            frag h;
            #pragma unroll
            for (int q = 0; q < 4; ++q) {
                f32x2 z = unpk2(gg.w[q]) + unpk2(yy.w[q]) + d2 * unpk2(dw.w[q]);
                f32x2 hv = gelu2(z);
                h.w[q] = pack_bf2(hv.x, hv.y);
            }
            *(bf16x8*)(h0buf + (ks * 64 + lane) * 16) = h.v;
        }
        __syncthreads();   // B: full H0 ready

        // ---- layer 1 (my 2 mt tiles): read full H0, TRANS -> F2loc ----
        frag F2loc[4];
        #pragma unroll
        for (int j = 0; j < 2; ++j) {
            const int mt = 2 * p + j;
            f32x16 acc;
            #pragma unroll
            for (int r = 0; r < 16; ++r) acc[r] = 0.f;
            #pragma unroll
            for (int ks = 0; ks < 8; ++ks) {
                bf16x8 a = *(const bf16x8*)(lds + OFF_W1 + ((mt * 8 + ks) * 64 + lane) * 16);
                bf16x8 h0 = *(const bf16x8*)(h0buf + (ks * 64 + lane) * 16);
                acc = MFMA(a, h0, acc);
            }
            TRANS_MT_PL(acc, mt, F2loc, 2 * j);
        }
        __syncthreads();   // C: all H0 reads done -> safe to overwrite with F2

        #pragma unroll
        for (int s = 0; s < 4; ++s)
            *(bf16x8*)(h0buf + ((4 * p + s) * 64 + lane) * 16) = F2loc[s].v;
        __syncthreads();   // D: full F2 ready

        // ---- per-node float edge mask (built once, reused by both nt tiles) ----
        f32x2 emask[8];
        #pragma unroll
        for (int q = 0; q < 8; ++q) {
            int e0 = ((2 * q) & 3) + 8 * (q >> 1) + 4 * hi;
            emask[q].x = (float)((vmask >> e0) & 1u);
            emask[q].y = (float)((vmask >> (e0 + 1)) & 1u);
        }

        // ---- layer 2 (my 2 nt tiles): A-frag from shared F2 in LDS ----
        float sres[2];
        #pragma unroll
        for (int j = 0; j < 2; ++j) {
            const int nt = 2 * p + j;
            f32x16 acc;
            #pragma unroll
            for (int r = 0; r < 16; ++r) acc[r] = 0.f;
            #pragma unroll
            for (int ks = 0; ks < 8; ++ks) {
                bf16x8 f2f = *(const bf16x8*)(h0buf + (ks * 64 + lane) * 16);
                bf16x8 w2f = *(const bf16x8*)(lds + OFF_W2 + ((nt * 8 + ks) * 64 + lane) * 16);
                acc = MFMA(f2f, w2f, acc);
            }
            float bv = s_b2f[nt * 32 + li];
            const f32x2 bv2 = {bv, bv};
            f32x2 tacc = {0.f, 0.f};
            #pragma unroll
            for (int q = 0; q < 8; ++q) {
                f32x2 av = {acc[2*q], acc[2*q+1]};
                f32x2 v2 = gelu2(av + bv2);
                tacc += v2 * emask[q];          // v_pk_fma_f32
            }
            float t = tacc.x + tacc.y;
            t += __shfl_xor(t, 32, 64);
            sres[j] = t;
        }

        // ---- epilogue: my feats are (2p)*32+li and (2p+1)*32+li ----
        int f0 = (2 * p) * 32 + li;
        int f1 = (2 * p + 1) * 32 + li;
        float u0 = (enc[(size_t)gnode * HH + f0] + sres[0] * inv_vc) * mask_n;
        float u1 = (enc[(size_t)gnode * HH + f1] + sres[1] * inv_vc) * mask_n;
        upd[(size_t)gnode * HH + f0] = u0;
        upd[(size_t)gnode * HH + f1] = u1;
        if (hi == 0) {
            st_s0 += u0; st_q0 = fmaf(u0, u0, st_q0);
            st_s1 += u1; st_q1 = fmaf(u1, u1, st_q1);
        }
    }

    // ---- fused stats: block partials per feature (reuses H0 region) ----
    __syncthreads();
    float4* red = (float4*)(lds + OFF_H0);
    red[tid] = (hi == 0) ? make_float4(st_s0, st_q0, st_s1, st_q1)
                         : make_float4(0.f, 0.f, 0.f, 0.f);
    __syncthreads();
    if (tid < HH) {
        const int f = tid;
        const int fp = f >> 6;
        const int fs = (f >> 5) & 1;
        const int fl = f & 31;
        float s = 0.f, sq = 0.f;
        #pragma unroll
        for (int w8 = 0; w8 < 8; ++w8) {
            float4 v = red[(2 * w8 + fp) * 64 + fl];
            s  += fs ? v.z : v.x;
            sq += fs ? v.w : v.y;
        }
        psum2[(size_t)blockIdx.x * HH + f]   = s;
        psumsq2[(size_t)blockIdx.x * HH + f] = sq;
    }
}

// ---------------------------------------------------------------------------
// Kernel 2b: combine per-block partials -> mean, 1/std per (b, feature)
// ---------------------------------------------------------------------------
__global__ __launch_bounds__(128) void finalize_stats_kernel(
    const float* __restrict__ psum2, const float* __restrict__ psumsq2,
    const float* __restrict__ mask, float* __restrict__ meanp, float* __restrict__ istdp)
{
    const int b = blockIdx.x;
    const int j = threadIdx.x;
    float s = 0.f, s2 = 0.f;
    #pragma unroll 4
    for (int c = 0; c < BPB; ++c) {
        s  += psum2[((size_t)(b * BPB + c)) * HH + j];
        s2 += psumsq2[((size_t)(b * BPB + c)) * HH + j];
    }
    float cpart = 0.f;
    #pragma unroll 4
    for (int t = 0; t < NN / HH; ++t)
        cpart += mask[(size_t)b * NN + (size_t)t * HH + j];
    __shared__ float red[HH];
    red[j] = cpart;
    __syncthreads();
    for (int off = HH / 2; off > 0; off >>= 1) {
        if (j < off) red[j] += red[j + off];
        __syncthreads();
    }
    float counts = red[0];
    if (counts == 0.f) counts = 1.f;
    float mean = s / counts;
    float var  = (s2 - 2.f * mean * s + (float)NN * mean * mean) / counts;
    meanp[b * HH + j] = mean;
    istdp[b * HH + j] = 1.0f / sqrtf(var + 1e-5f);
}

// ---------------------------------------------------------------------------
// Kernel 3: normalize out0 in place + write pass-through outputs
// ---------------------------------------------------------------------------
__global__ void write_out_kernel(
    const float* __restrict__ mask, const float* __restrict__ dist,
    const int* __restrict__ eidx, const float* __restrict__ meanp,
    const float* __restrict__ istdp, const float* __restrict__ scale,
    const float* __restrict__ shift, float* __restrict__ out)
{
    const size_t T0 = (size_t)BB * NN * HH;
    const size_t T1 = (size_t)BB * NN;
    const size_t T2 = (size_t)BB * NN * KK;
    const size_t stride = (size_t)gridDim.x * blockDim.x;
    const size_t t = (size_t)blockIdx.x * blockDim.x + threadIdx.x;

    for (size_t x = t; x < T0; x += stride) {
        int h = (int)(x & (HH - 1));
        size_t bn = x >> 7;
        int b = (int)(bn >> 12);
        float m = mask[bn];
        float v = (out[x] - meanp[b * HH + h]) * istdp[b * HH + h] * scale[h] + shift[h];
        out[x] = v * m;
    }
    float* out1 = out + T0;
    for (size_t x = t; x < T1; x += stride) out1[x] = mask[x];
    float* out2 = out1 + T1;
    for (size_t x = t; x < T2; x += stride) out2[x] = dist[x];
    float* out3 = out2 + T2;
    for (size_t x = t; x < T2; x += stride) out3[x] = (float)eidx[x];
}

// ---------------------------------------------------------------------------
extern "C" void kernel_launch(void* const* d_in, const int* in_sizes, int n_in,
                              void* d_out, int out_size, void* d_ws, size_t ws_size,
                              hipStream_t stream) {
    const float* enc   = (const float*)d_in[0];
    const float* mask  = (const float*)d_in[1];
    const float* dist  = (const float*)d_in[2];
    const int*   eidx  = (const int*)  d_in[3];
    const float* W0    = (const float*)d_in[4];
    const float* b0    = (const float*)d_in[5];
    const float* W1    = (const float*)d_in[6];
    const float* b1    = (const float*)d_in[7];
    const float* W2    = (const float*)d_in[8];
    const float* b2    = (const float*)d_in[9];
    const float* scale = (const float*)d_in[10];
    const float* shift = (const float*)d_in[11];
    float* out = (float*)d_out;
    float* upd = out;   // pre-norm upd lives in out[0:B*N*H], normalized in place later

    const size_t T0 = (size_t)BB * NN * HH;
    const size_t T1 = (size_t)BB * NN;

    __hip_bfloat16* Ysrc  = (__hip_bfloat16*)d_ws;                 // 4 MB
    __hip_bfloat16* Yself = (__hip_bfloat16*)(out + T0 + T1);      // 4 MB (out2/out3 region, overwritten last)
    float* wsf     = (float*)((char*)d_ws + (size_t)BB * NN * HH * 2);
    float* psum2   = wsf;                                          // 128 KB
    float* psumsq2 = psum2 + (size_t)NBLK * HH;                    // 128 KB
    float* meanp   = psumsq2 + (size_t)NBLK * HH;
    float* istdp   = meanp + (size_t)BB * HH;
    short* W0t     = (short*)(istdp + (size_t)BB * HH);            // 64 KB

    hipFuncSetAttribute((const void*)mpnn_kernel,
                        hipFuncAttributeMaxDynamicSharedMemorySize, LDS_TOTAL);

    prep_w0_kernel<<<dim3(128), dim3(256), 0, stream>>>(W0, W0t);
    precompute_kernel<<<dim3(256), dim3(128), 0, stream>>>(enc, mask, W0t, b0, Ysrc, Yself);
    mpnn_kernel<<<dim3(NBLK), dim3(THREADS), LDS_TOTAL, stream>>>(
        enc, mask, dist, eidx, Ysrc, Yself, W0, W1, b1, W2, b2, upd, psum2, psumsq2);
    finalize_stats_kernel<<<dim3(BB), dim3(128), 0, stream>>>(psum2, psumsq2, mask, meanp, istdp);
    write_out_kernel<<<dim3(1024), dim3(256), 0, stream>>>(
        mask, dist, eidx, meanp, istdp, scale, shift, out);
}